// Round 1
// baseline (5336.639 us; speedup 1.0000x reference)
//
#include <hip/hip_runtime.h>

#define N_NODES 100000
#define N_EDGES 3200000
#define D_FEAT  128

// Edge-parallel COO SpMM with fp32 atomics.
// 32 threads per edge: lane f4 handles float4 #f4 of the 128-feature row.
// Gather x[col] is one contiguous 512B segment per edge (coalesced);
// scatter uses native global_atomic_add_f32 via unsafeAtomicAdd.
__global__ __launch_bounds__(256) void spmm_atomic_kernel(
    const float* __restrict__ x,
    const int*   __restrict__ adj_rows,
    const int*   __restrict__ adj_cols,
    const float* __restrict__ adj_vals,
    const int*   __restrict__ idx_p,
    float*       __restrict__ out)
{
    const long long idx = (long long)idx_p[0];
    const int*   rows = adj_rows + idx * (long long)N_EDGES;
    const int*   cols = adj_cols + idx * (long long)N_EDGES;
    const float* vals = adj_vals + idx * (long long)N_EDGES;

    long long t  = (long long)blockIdx.x * blockDim.x + threadIdx.x;
    long long e  = t >> 5;          // edge index (32 threads per edge)
    int       f4 = (int)(t & 31);   // which float4 chunk (0..31)
    if (e >= N_EDGES) return;

    const int   r = rows[e];
    const int   c = cols[e];
    const float v = vals[e];

    const float4 xv =
        *reinterpret_cast<const float4*>(x + (long long)c * D_FEAT + f4 * 4);

    float* o = out + (long long)r * D_FEAT + f4 * 4;
    unsafeAtomicAdd(o + 0, v * xv.x);
    unsafeAtomicAdd(o + 1, v * xv.y);
    unsafeAtomicAdd(o + 2, v * xv.z);
    unsafeAtomicAdd(o + 3, v * xv.w);
}

extern "C" void kernel_launch(void* const* d_in, const int* in_sizes, int n_in,
                              void* d_out, int out_size, void* d_ws, size_t ws_size,
                              hipStream_t stream) {
    const float* x        = (const float*)d_in[0];
    const int*   adj_rows = (const int*)  d_in[1];
    const int*   adj_cols = (const int*)  d_in[2];
    const float* adj_vals = (const float*)d_in[3];
    const int*   idx_p    = (const int*)  d_in[4];
    float*       out      = (float*)d_out;

    // Zero the output (harness poisons it; atomics accumulate into it).
    hipMemsetAsync(out, 0, (size_t)out_size * sizeof(float), stream);

    const long long total_threads = (long long)N_EDGES * 32;
    const int block = 256;
    const long long grid = (total_threads + block - 1) / block;

    spmm_atomic_kernel<<<(dim3)(unsigned)grid, block, 0, stream>>>(
        x, adj_rows, adj_cols, adj_vals, idx_p, out);
}

// Round 2
// 806.168 us; speedup vs baseline: 6.6198x; 6.6198x over previous
//
#include <hip/hip_runtime.h>

#define N_NODES 100000
#define N_EDGES 3200000
#define D_FEAT  128

// ---------------------------------------------------------------------------
// Strategy: per-call counting sort of edges by destination row (CSR build in
// d_ws), then CSR SpMM with one wave64 per row (register accumulation, one
// coalesced write per row). Only int atomics on 100K counters remain.
// ---------------------------------------------------------------------------

// Kernel 1: histogram of row indices.
__global__ __launch_bounds__(256) void hist_kernel(
    const int* __restrict__ adj_rows, const int* __restrict__ idx_p,
    int* __restrict__ hist)
{
    const long long idx = (long long)idx_p[0];
    const int* rows = adj_rows + idx * (long long)N_EDGES;
    for (int e = blockIdx.x * blockDim.x + threadIdx.x; e < N_EDGES;
         e += gridDim.x * blockDim.x)
        atomicAdd(&hist[rows[e]], 1);
}

// Kernel 2: single-block exclusive scan (100K elems) -> rowptr, cursor.
__global__ __launch_bounds__(1024) void exscan_kernel(
    const int* __restrict__ hist, int* __restrict__ rowptr,
    int* __restrict__ cursor)
{
    __shared__ int lds[1024];
    int carry = 0;  // wave-uniform running total (same value in all threads)
    for (int base = 0; base < N_NODES; base += 1024) {
        const int i = base + (int)threadIdx.x;
        const int v = (i < N_NODES) ? hist[i] : 0;
        lds[threadIdx.x] = v;
        __syncthreads();
        // Hillis-Steele inclusive scan in LDS.
        for (int off = 1; off < 1024; off <<= 1) {
            int t = (threadIdx.x >= (unsigned)off) ? lds[threadIdx.x - off] : 0;
            __syncthreads();
            lds[threadIdx.x] += t;
            __syncthreads();
        }
        const int incl = lds[threadIdx.x];
        const int excl = incl - v;
        if (i < N_NODES) {
            rowptr[i] = carry + excl;
            cursor[i] = carry + excl;
        }
        const int total = lds[1023];
        __syncthreads();
        carry += total;
    }
    if (threadIdx.x == 0) rowptr[N_NODES] = carry;
}

// Kernel 3: scatter (col,val) pairs into row-sorted order.
__global__ __launch_bounds__(256) void scatter_kernel(
    const int* __restrict__ adj_rows, const int* __restrict__ adj_cols,
    const float* __restrict__ adj_vals, const int* __restrict__ idx_p,
    int* __restrict__ cursor, int* __restrict__ scol, float* __restrict__ sval)
{
    const long long idx = (long long)idx_p[0];
    const int*   rows = adj_rows + idx * (long long)N_EDGES;
    const int*   cols = adj_cols + idx * (long long)N_EDGES;
    const float* vals = adj_vals + idx * (long long)N_EDGES;
    for (int e = blockIdx.x * blockDim.x + threadIdx.x; e < N_EDGES;
         e += gridDim.x * blockDim.x) {
        const int r   = rows[e];
        const int pos = atomicAdd(&cursor[r], 1);
        scol[pos] = cols[e];
        sval[pos] = vals[e];
    }
}

// Kernel 4: CSR SpMM, one wave64 per row. Lane handles 2 consecutive floats.
__global__ __launch_bounds__(256) void csr_spmm_kernel(
    const float* __restrict__ x, const int* __restrict__ rowptr,
    const int* __restrict__ scol, const float* __restrict__ sval,
    float* __restrict__ out)
{
    const int wave = (int)(blockIdx.x * (blockDim.x >> 6) + (threadIdx.x >> 6));
    const int lane = (int)(threadIdx.x & 63);
    if (wave >= N_NODES) return;

    const int start = rowptr[wave];
    const int end   = rowptr[wave + 1];

    float2 acc = {0.f, 0.f};
    for (int chunk = start; chunk < end; chunk += 64) {
        const int n = min(64, end - chunk);
        int   c = 0;
        float v = 0.f;
        if (lane < n) {
            c = scol[chunk + lane];   // one coalesced load per 64 edges
            v = sval[chunk + lane];
        }
        for (int j = 0; j < n; ++j) {
            const int   cj = __shfl(c, j);
            const float vj = __shfl(v, j);
            const float2 xv = *reinterpret_cast<const float2*>(
                x + (long long)cj * D_FEAT + lane * 2);
            acc.x += vj * xv.x;
            acc.y += vj * xv.y;
        }
    }
    *reinterpret_cast<float2*>(out + (long long)wave * D_FEAT + lane * 2) = acc;
}

// Fallback (tiny workspace): original edge-parallel atomic kernel.
__global__ __launch_bounds__(256) void spmm_atomic_kernel(
    const float* __restrict__ x,
    const int*   __restrict__ adj_rows,
    const int*   __restrict__ adj_cols,
    const float* __restrict__ adj_vals,
    const int*   __restrict__ idx_p,
    float*       __restrict__ out)
{
    const long long idx = (long long)idx_p[0];
    const int*   rows = adj_rows + idx * (long long)N_EDGES;
    const int*   cols = adj_cols + idx * (long long)N_EDGES;
    const float* vals = adj_vals + idx * (long long)N_EDGES;

    long long t  = (long long)blockIdx.x * blockDim.x + threadIdx.x;
    long long e  = t >> 5;
    int       f4 = (int)(t & 31);
    if (e >= N_EDGES) return;

    const int   r = rows[e];
    const int   c = cols[e];
    const float v = vals[e];
    const float4 xv =
        *reinterpret_cast<const float4*>(x + (long long)c * D_FEAT + f4 * 4);
    float* o = out + (long long)r * D_FEAT + f4 * 4;
    unsafeAtomicAdd(o + 0, v * xv.x);
    unsafeAtomicAdd(o + 1, v * xv.y);
    unsafeAtomicAdd(o + 2, v * xv.z);
    unsafeAtomicAdd(o + 3, v * xv.w);
}

extern "C" void kernel_launch(void* const* d_in, const int* in_sizes, int n_in,
                              void* d_out, int out_size, void* d_ws, size_t ws_size,
                              hipStream_t stream) {
    const float* x        = (const float*)d_in[0];
    const int*   adj_rows = (const int*)  d_in[1];
    const int*   adj_cols = (const int*)  d_in[2];
    const float* adj_vals = (const float*)d_in[3];
    const int*   idx_p    = (const int*)  d_in[4];
    float*       out      = (float*)d_out;

    // Workspace layout (all 4-byte elements):
    //   hist/then-unused : N_NODES+1 ints   (histogram; memset each call)
    //   rowptr           : N_NODES+1 ints
    //   cursor           : N_NODES   ints
    //   scol             : N_EDGES   ints
    //   sval             : N_EDGES   floats
    const size_t need = (size_t)((N_NODES + 1) * 2 + N_NODES + 2 * N_EDGES) * 4;

    if (ws_size < need) {
        // Fallback: atomic scatter version.
        hipMemsetAsync(out, 0, (size_t)out_size * sizeof(float), stream);
        const long long total_threads = (long long)N_EDGES * 32;
        const int block = 256;
        const long long grid = (total_threads + block - 1) / block;
        spmm_atomic_kernel<<<(dim3)(unsigned)grid, block, 0, stream>>>(
            x, adj_rows, adj_cols, adj_vals, idx_p, out);
        return;
    }

    int*   hist   = (int*)d_ws;
    int*   rowptr = hist + (N_NODES + 1);
    int*   cursor = rowptr + (N_NODES + 1);
    int*   scol   = cursor + N_NODES;
    float* sval   = (float*)(scol + N_EDGES);

    hipMemsetAsync(hist, 0, (size_t)(N_NODES + 1) * sizeof(int), stream);

    hist_kernel<<<2048, 256, 0, stream>>>(adj_rows, idx_p, hist);
    exscan_kernel<<<1, 1024, 0, stream>>>(hist, rowptr, cursor);
    scatter_kernel<<<2048, 256, 0, stream>>>(adj_rows, adj_cols, adj_vals,
                                             idx_p, cursor, scol, sval);

    const int rows_per_block = 256 / 64;  // 4 waves per block
    const int grid = (N_NODES + rows_per_block - 1) / rows_per_block;
    csr_spmm_kernel<<<grid, 256, 0, stream>>>(x, rowptr, scol, sval, out);
}

// Round 3
// 624.180 us; speedup vs baseline: 8.5498x; 1.2916x over previous
//
#include <hip/hip_runtime.h>

#define N_NODES 100000
#define N_EDGES 3200000
#define D_FEAT  128

#define SCAN_CHUNK 1024
#define NCHUNK ((N_NODES + SCAN_CHUNK - 1) / SCAN_CHUNK)   // 98

// ---------------------------------------------------------------------------
// Counting sort by destination row (CSR build in d_ws), then CSR SpMM with
// one wave64 per row. (col,val) pairs are packed into int2 so the random
// scatter touches one cache line per edge, not two. The exclusive scan of
// the 100K-row histogram is a parallel 3-kernel scan.
// ---------------------------------------------------------------------------

// Kernel 1: histogram of row indices.
__global__ __launch_bounds__(256) void hist_kernel(
    const int* __restrict__ adj_rows, const int* __restrict__ idx_p,
    int* __restrict__ hist)
{
    const long long idx = (long long)idx_p[0];
    const int* rows = adj_rows + idx * (long long)N_EDGES;
    for (int e = blockIdx.x * blockDim.x + threadIdx.x; e < N_EDGES;
         e += gridDim.x * blockDim.x)
        atomicAdd(&hist[rows[e]], 1);
}

// Kernel 2a: per-chunk reduction (1024 elems per block of 256 threads).
__global__ __launch_bounds__(256) void chunk_reduce_kernel(
    const int* __restrict__ hist, int* __restrict__ chunk_sum)
{
    __shared__ int lds[256];
    const int b = blockIdx.x;
    const int t = threadIdx.x;
    const int base = b * SCAN_CHUNK + t * 4;
    int s = 0;
#pragma unroll
    for (int k = 0; k < 4; ++k) {
        const int i = base + k;
        if (i < N_NODES) s += hist[i];
    }
    lds[t] = s;
    __syncthreads();
    for (int off = 128; off > 0; off >>= 1) {
        if (t < off) lds[t] += lds[t + off];
        __syncthreads();
    }
    if (t == 0) chunk_sum[b] = lds[0];
}

// Kernel 2b: exclusive scan of the NCHUNK (=98) chunk sums, single block.
__global__ __launch_bounds__(128) void scan_sums_kernel(
    const int* __restrict__ chunk_sum, int* __restrict__ chunk_off,
    int* __restrict__ rowptr)
{
    __shared__ int lds[128];
    const int t = threadIdx.x;
    const int v = (t < NCHUNK) ? chunk_sum[t] : 0;
    lds[t] = v;
    __syncthreads();
    for (int off = 1; off < 128; off <<= 1) {
        int u = (t >= off) ? lds[t - off] : 0;
        __syncthreads();
        lds[t] += u;
        __syncthreads();
    }
    const int incl = lds[t];
    if (t < NCHUNK) chunk_off[t] = incl - v;
    if (t == NCHUNK - 1) rowptr[N_NODES] = incl;
}

// Kernel 2c: per-chunk exclusive scan + chunk offset -> rowptr, cursor.
__global__ __launch_bounds__(256) void chunk_scan_kernel(
    const int* __restrict__ hist, const int* __restrict__ chunk_off,
    int* __restrict__ rowptr, int* __restrict__ cursor)
{
    __shared__ int lds[256];
    const int b = blockIdx.x;
    const int t = threadIdx.x;
    const int base = b * SCAN_CHUNK + t * 4;
    int v[4];
    int s = 0;
#pragma unroll
    for (int k = 0; k < 4; ++k) {
        const int i = base + k;
        v[k] = (i < N_NODES) ? hist[i] : 0;
        s += v[k];
    }
    lds[t] = s;
    __syncthreads();
    for (int off = 1; off < 256; off <<= 1) {
        int u = (t >= off) ? lds[t - off] : 0;
        __syncthreads();
        lds[t] += u;
        __syncthreads();
    }
    int run = chunk_off[b] + lds[t] - s;   // exclusive prefix for this thread
#pragma unroll
    for (int k = 0; k < 4; ++k) {
        const int i = base + k;
        if (i < N_NODES) {
            rowptr[i] = run;
            cursor[i] = run;
        }
        run += v[k];
    }
}

// Kernel 3: scatter packed (col,val) into row-sorted order.
__global__ __launch_bounds__(256) void scatter_kernel(
    const int* __restrict__ adj_rows, const int* __restrict__ adj_cols,
    const float* __restrict__ adj_vals, const int* __restrict__ idx_p,
    int* __restrict__ cursor, int2* __restrict__ pairs)
{
    const long long idx = (long long)idx_p[0];
    const int*   rows = adj_rows + idx * (long long)N_EDGES;
    const int*   cols = adj_cols + idx * (long long)N_EDGES;
    const float* vals = adj_vals + idx * (long long)N_EDGES;
    for (int e = blockIdx.x * blockDim.x + threadIdx.x; e < N_EDGES;
         e += gridDim.x * blockDim.x) {
        const int r   = rows[e];
        const int pos = atomicAdd(&cursor[r], 1);
        pairs[pos] = make_int2(cols[e], __float_as_int(vals[e]));
    }
}

// Kernel 4: CSR SpMM, one wave64 per row. Lane handles 2 consecutive floats.
__global__ __launch_bounds__(256) void csr_spmm_kernel(
    const float* __restrict__ x, const int* __restrict__ rowptr,
    const int2* __restrict__ pairs, float* __restrict__ out)
{
    const int wave = (int)(blockIdx.x * (blockDim.x >> 6) + (threadIdx.x >> 6));
    const int lane = (int)(threadIdx.x & 63);
    if (wave >= N_NODES) return;

    const int start = rowptr[wave];
    const int end   = rowptr[wave + 1];

    float2 acc = {0.f, 0.f};
    for (int chunk = start; chunk < end; chunk += 64) {
        const int n = min(64, end - chunk);
        int   c = 0;
        float v = 0.f;
        if (lane < n) {
            const int2 p = pairs[chunk + lane];   // one coalesced 8B load
            c = p.x;
            v = __int_as_float(p.y);
        }
#pragma unroll 4
        for (int j = 0; j < n; ++j) {
            const int   cj = __shfl(c, j);
            const float vj = __shfl(v, j);
            const float2 xv = *reinterpret_cast<const float2*>(
                x + (long long)cj * D_FEAT + lane * 2);
            acc.x += vj * xv.x;
            acc.y += vj * xv.y;
        }
    }
    *reinterpret_cast<float2*>(out + (long long)wave * D_FEAT + lane * 2) = acc;
}

// Fallback (tiny workspace): edge-parallel atomic kernel.
__global__ __launch_bounds__(256) void spmm_atomic_kernel(
    const float* __restrict__ x,
    const int*   __restrict__ adj_rows,
    const int*   __restrict__ adj_cols,
    const float* __restrict__ adj_vals,
    const int*   __restrict__ idx_p,
    float*       __restrict__ out)
{
    const long long idx = (long long)idx_p[0];
    const int*   rows = adj_rows + idx * (long long)N_EDGES;
    const int*   cols = adj_cols + idx * (long long)N_EDGES;
    const float* vals = adj_vals + idx * (long long)N_EDGES;

    long long t  = (long long)blockIdx.x * blockDim.x + threadIdx.x;
    long long e  = t >> 5;
    int       f4 = (int)(t & 31);
    if (e >= N_EDGES) return;

    const int   r = rows[e];
    const int   c = cols[e];
    const float v = vals[e];
    const float4 xv =
        *reinterpret_cast<const float4*>(x + (long long)c * D_FEAT + f4 * 4);
    float* o = out + (long long)r * D_FEAT + f4 * 4;
    unsafeAtomicAdd(o + 0, v * xv.x);
    unsafeAtomicAdd(o + 1, v * xv.y);
    unsafeAtomicAdd(o + 2, v * xv.z);
    unsafeAtomicAdd(o + 3, v * xv.w);
}

extern "C" void kernel_launch(void* const* d_in, const int* in_sizes, int n_in,
                              void* d_out, int out_size, void* d_ws, size_t ws_size,
                              hipStream_t stream) {
    const float* x        = (const float*)d_in[0];
    const int*   adj_rows = (const int*)  d_in[1];
    const int*   adj_cols = (const int*)  d_in[2];
    const float* adj_vals = (const float*)d_in[3];
    const int*   idx_p    = (const int*)  d_in[4];
    float*       out      = (float*)d_out;

    // Workspace layout (4-byte elements):
    //   hist      : N_NODES+1
    //   rowptr    : N_NODES+1
    //   cursor    : N_NODES
    //   chunk_sum : 128
    //   chunk_off : 128
    //   pairs     : N_EDGES int2 (8B-aligned: preceding count is even)
    const size_t n_meta = (size_t)(N_NODES + 1) * 2 + N_NODES + 256;
    const size_t need   = (n_meta + (size_t)2 * N_EDGES) * 4;

    if (ws_size < need) {
        hipMemsetAsync(out, 0, (size_t)out_size * sizeof(float), stream);
        const long long total_threads = (long long)N_EDGES * 32;
        const int block = 256;
        const long long grid = (total_threads + block - 1) / block;
        spmm_atomic_kernel<<<(dim3)(unsigned)grid, block, 0, stream>>>(
            x, adj_rows, adj_cols, adj_vals, idx_p, out);
        return;
    }

    int*  hist      = (int*)d_ws;
    int*  rowptr    = hist + (N_NODES + 1);
    int*  cursor    = rowptr + (N_NODES + 1);
    int*  chunk_sum = cursor + N_NODES;
    int*  chunk_off = chunk_sum + 128;
    int2* pairs     = (int2*)(chunk_off + 128);

    hipMemsetAsync(hist, 0, (size_t)(N_NODES + 1) * sizeof(int), stream);

    hist_kernel<<<2048, 256, 0, stream>>>(adj_rows, idx_p, hist);
    chunk_reduce_kernel<<<NCHUNK, 256, 0, stream>>>(hist, chunk_sum);
    scan_sums_kernel<<<1, 128, 0, stream>>>(chunk_sum, chunk_off, rowptr);
    chunk_scan_kernel<<<NCHUNK, 256, 0, stream>>>(hist, chunk_off, rowptr, cursor);
    scatter_kernel<<<2048, 256, 0, stream>>>(adj_rows, adj_cols, adj_vals,
                                             idx_p, cursor, pairs);

    const int rows_per_block = 256 / 64;  // 4 waves per block
    const int grid = (N_NODES + rows_per_block - 1) / rows_per_block;
    csr_spmm_kernel<<<grid, 256, 0, stream>>>(x, rowptr, pairs, out);
}